// Round 4
// baseline (159.201 us; speedup 1.0000x reference)
//
#include <hip/hip_runtime.h>
#include <math.h>

#define B_SZ 64
#define SEQ 2048
#define DM 12
#define DI 24
#define DS 16
#define DC 4
#define DTR 4
#define NSEG 32
#define SEGLEN 64
#define LP 68   /* SEGLEN + 4: row = 272 B = 17x16 B, float4-aligned rows, bank-skewed */

__device__ __forceinline__ float silu_f(float v) { return v / (1.f + __expf(-v)); }
__device__ __forceinline__ float softplus_f(float v) {
    return fmaxf(v, 0.f) + __logf(1.f + __expf(-fabsf(v)));
}
__device__ __forceinline__ float dot12(const float4 w[3], float4 r0, float4 r1, float4 r2) {
    float s = 0.f;
    s = fmaf(w[0].x, r0.x, s); s = fmaf(w[0].y, r0.y, s);
    s = fmaf(w[0].z, r0.z, s); s = fmaf(w[0].w, r0.w, s);
    s = fmaf(w[1].x, r1.x, s); s = fmaf(w[1].y, r1.y, s);
    s = fmaf(w[1].z, r1.z, s); s = fmaf(w[1].w, r1.w, s);
    s = fmaf(w[2].x, r2.x, s); s = fmaf(w[2].y, r2.y, s);
    s = fmaf(w[2].z, r2.z, s); s = fmaf(w[2].w, r2.w, s);
    return s;
}

// Single kernel. One block per (batch, segment), 384 threads.
// Phases A-C: thread = (j = tid>>6 in [0,6), t = tid&63); owns channels 4j..4j+3.
// Scan: thread = (d = tid>>4, s = tid&15).
// Last block per batch (semaphore) combines the 32 segments + runs the epilogue.
__global__ __launch_bounds__(384) void mamba_one_kernel(
    const float* __restrict__ x, const float* __restrict__ ipw,
    const float* __restrict__ cw, const float* __restrict__ cb,
    const float* __restrict__ xpw, const float* __restrict__ dpw,
    const float* __restrict__ dpb, const float* __restrict__ A_log,
    const float* __restrict__ Dv, const float* __restrict__ opw,
    const float* __restrict__ fcw, const float* __restrict__ fcb,
    float* __restrict__ segA, float* __restrict__ segB,
    int* __restrict__ cnt, float* __restrict__ out)
{
    __shared__ __align__(16) float xin_s[DI][LP];  // xin in A; du = dt*xc after C
    __shared__ __align__(16) float xc_s[DI][LP];
    __shared__ __align__(16) float dts[DI][LP];
    __shared__ __align__(16) float Bs[DS][LP];
    __shared__ __align__(16) float dtr_s[DTR][LP];
    __shared__ int is_last;

    const int tid = threadIdx.x;
    const int b = blockIdx.x >> 5, seg = blockIdx.x & 31;
    const int t0 = seg * SEGLEN;
    const int j = tid >> 6;       // wave index 0..5
    const int t = tid & 63;
    const int d0 = j * 4;

    const float Aval = -__expf(A_log[tid]);  // scan phase: tid = d*16+s

    // ---- Phase A1: xin = in_proj(x) once per (d,t); cols stored at t+3 ----
    float4 wA[4][3];
    float cwr[4][4], cbr[4];
    {
#pragma unroll
        for (int i = 0; i < 4; ++i) {
            const float4* wp = (const float4*)(ipw + (d0 + i) * DM);
            wA[i][0] = wp[0]; wA[i][1] = wp[1]; wA[i][2] = wp[2];
            const float4 cw4 = *(const float4*)(cw + (d0 + i) * DC);
            cwr[i][0] = cw4.x; cwr[i][1] = cw4.y; cwr[i][2] = cw4.z; cwr[i][3] = cw4.w;
            cbr[i] = cb[d0 + i];
        }
        const float4* xp = (const float4*)(x + ((size_t)b * SEQ + (t0 + t)) * DM);
        float4 r0 = xp[0], r1 = xp[1], r2 = xp[2];
#pragma unroll
        for (int i = 0; i < 4; ++i) xin_s[d0 + i][t + 3] = dot12(wA[i], r0, r1, r2);
        if (t < 3) {                       // 3-column halo
            int gt = t0 + t - 3;
            float4 h0, h1, h2;
            if (gt >= 0) {
                const float4* hp = (const float4*)(x + ((size_t)b * SEQ + gt) * DM);
                h0 = hp[0]; h1 = hp[1]; h2 = hp[2];
            } else {
                h0 = make_float4(0.f, 0.f, 0.f, 0.f); h1 = h0; h2 = h0;
            }
#pragma unroll
            for (int i = 0; i < 4; ++i) xin_s[d0 + i][t] = dot12(wA[i], h0, h1, h2);
        }
    }
    __syncthreads();

    // ---- Phase A2: causal conv + silu ----
    float xc_loc[4];
    {
#pragma unroll
        for (int i = 0; i < 4; ++i) {
            float acc = cbr[i];
#pragma unroll
            for (int k = 0; k < DC; ++k)
                acc = fmaf(cwr[i][k], xin_s[d0 + i][t + k], acc);
            float v = silu_f(acc);
            xc_loc[i] = v;
            xc_s[d0 + i][t] = v;
        }
    }
    __syncthreads();

    // ---- Phase B: x_proj rows r == j (mod 6); rows 0..3 -> dt_raw, 4..19 -> B ----
    {
        float xc[DI];
#pragma unroll
        for (int d = 0; d < DI; ++d) xc[d] = xc_s[d][t];
        for (int r = j; r < DTR + DS; r += 6) {
            const float4* wr = (const float4*)(xpw + r * DI);
            float4 w4[6];
#pragma unroll
            for (int c = 0; c < 6; ++c) w4[c] = wr[c];
            float s = 0.f;
#pragma unroll
            for (int c = 0; c < 6; ++c) {
                s = fmaf(w4[c].x, xc[4 * c + 0], s);
                s = fmaf(w4[c].y, xc[4 * c + 1], s);
                s = fmaf(w4[c].z, xc[4 * c + 2], s);
                s = fmaf(w4[c].w, xc[4 * c + 3], s);
            }
            if (r < DTR) dtr_s[r][t] = s;
            else         Bs[r - DTR][t] = s;
        }
    }
    __syncthreads();

    // ---- Phase C: dt = softplus(dt_raw @ dpw^T + dpb); du = dt*xc (into xin_s) ----
    {
        float dtr[DTR];
#pragma unroll
        for (int r = 0; r < DTR; ++r) dtr[r] = dtr_s[r][t];
#pragma unroll
        for (int i = 0; i < 4; ++i) {
            int d = d0 + i;
            const float4 w4 = *(const float4*)(dpw + d * DTR);
            float s = dpb[d];
            s = fmaf(dtr[0], w4.x, s); s = fmaf(dtr[1], w4.y, s);
            s = fmaf(dtr[2], w4.z, s); s = fmaf(dtr[3], w4.w, s);
            float dt = softplus_f(s);
            dts[d][t] = dt;
            xin_s[d][t] = dt * xc_loc[i];   // du
        }
    }
    __syncthreads();

    // ---- Scan: affine segment reduction over 64 steps ----
    {
        const int d = tid >> 4, s = tid & 15;
        float a_acc = 1.f, b_acc = 0.f;
        const float4* dtp = (const float4*)&dts[d][0];
        const float4* dup = (const float4*)&xin_s[d][0];
        const float4* Bp  = (const float4*)&Bs[s][0];
#pragma unroll 4
        for (int i = 0; i < SEGLEN / 4; ++i) {
            float4 dt4 = dtp[i], du4 = dup[i], B4 = Bp[i];
            float a;
            a = __expf(dt4.x * Aval); b_acc = fmaf(a, b_acc, du4.x * B4.x); a_acc *= a;
            a = __expf(dt4.y * Aval); b_acc = fmaf(a, b_acc, du4.y * B4.y); a_acc *= a;
            a = __expf(dt4.z * Aval); b_acc = fmaf(a, b_acc, du4.z * B4.z); a_acc *= a;
            a = __expf(dt4.w * Aval); b_acc = fmaf(a, b_acc, du4.w * B4.w); a_acc *= a;
        }
        size_t o = (size_t)blockIdx.x * (DI * DS) + tid;
        segA[o] = a_acc;
        segB[o] = b_acc;
    }
    __syncthreads();   // all stores issued (barrier drains vmcnt)

    // ---- Semaphore: last block for this batch does combine + epilogue ----
    if (tid == 0) {
        __threadfence();                       // release our segA/segB stores
        int old = atomicAdd(&cnt[b], 1);
        is_last = (old == NSEG - 1);
        if (is_last) __threadfence();          // acquire others' stores
    }
    __syncthreads();
    if (!is_last) return;

    __shared__ float h_sh[DI * DS];
    __shared__ float xcl[DI], CL[DS], zv[DI], yv[DI], ov[DM];

    float h = 0.f;
#pragma unroll
    for (int g = 0; g < NSEG; ++g) {
        size_t o = ((size_t)(b * NSEG + g)) * (DI * DS) + tid;
        h = fmaf(segA[o], h, segB[o]);
    }
    h_sh[tid] = h;

    const float* xr = x + ((size_t)b * SEQ + SEQ - 1) * DM;
    if (tid < DI) {
        float acc = cb[tid];
#pragma unroll
        for (int k = 0; k < DC; ++k) {
            const float* row = x + ((size_t)b * SEQ + (SEQ - DC + k)) * DM;
            float xin = 0.f;
#pragma unroll
            for (int m = 0; m < DM; ++m) xin = fmaf(row[m], ipw[tid * DM + m], xin);
            acc = fmaf(xin, cw[tid * DC + k], acc);
        }
        xcl[tid] = silu_f(acc);
        float s = 0.f;
#pragma unroll
        for (int m = 0; m < DM; ++m) s = fmaf(xr[m], ipw[(DI + tid) * DM + m], s);
        zv[tid] = s;
    }
    __syncthreads();

    if (tid < DS) {
        float s = 0.f;
#pragma unroll
        for (int d = 0; d < DI; ++d) s = fmaf(xcl[d], xpw[(DTR + DS + tid) * DI + d], s);
        CL[tid] = s;
    }
    __syncthreads();

    if (tid < DI) {
        float y = 0.f;
#pragma unroll
        for (int s2 = 0; s2 < DS; ++s2) y = fmaf(h_sh[tid * DS + s2], CL[s2], y);
        y = fmaf(xcl[tid], Dv[tid], y);
        yv[tid] = y * silu_f(zv[tid]);
    }
    __syncthreads();

    if (tid < DM) {
        float s = 0.f;
#pragma unroll
        for (int d = 0; d < DI; ++d) s = fmaf(yv[d], opw[tid * DI + d], s);
        ov[tid] = s;
    }
    __syncthreads();

    if (tid == 0) {
        float s = fcb[0];
#pragma unroll
        for (int e = 0; e < DM; ++e) s = fmaf(ov[e], fcw[e], s);
        out[b] = s;
    }
}

extern "C" void kernel_launch(void* const* d_in, const int* in_sizes, int n_in,
                              void* d_out, int out_size, void* d_ws, size_t ws_size,
                              hipStream_t stream)
{
    const float* x   = (const float*)d_in[0];
    const float* ipw = (const float*)d_in[1];
    const float* cw  = (const float*)d_in[2];
    const float* cb  = (const float*)d_in[3];
    const float* xpw = (const float*)d_in[4];
    const float* dpw = (const float*)d_in[5];
    const float* dpb = (const float*)d_in[6];
    const float* Al  = (const float*)d_in[7];
    const float* Dv  = (const float*)d_in[8];
    const float* opw = (const float*)d_in[9];
    const float* fcw = (const float*)d_in[10];
    const float* fcb = (const float*)d_in[11];

    float* segA = (float*)d_ws;                           // [B*NSEG][384]
    float* segB = segA + (size_t)B_SZ * NSEG * DI * DS;
    int*   cnt  = (int*)(segB + (size_t)B_SZ * NSEG * DI * DS);

    hipMemsetAsync(cnt, 0, B_SZ * sizeof(int), stream);
    mamba_one_kernel<<<B_SZ * NSEG, 384, 0, stream>>>(
        x, ipw, cw, cb, xpw, dpw, dpb, Al, Dv, opw, fcw, fcb,
        segA, segB, cnt, (float*)d_out);
}

// Round 5
// 109.514 us; speedup vs baseline: 1.4537x; 1.4537x over previous
//
#include <hip/hip_runtime.h>
#include <math.h>

#define B_SZ 64
#define SEQ 2048
#define DM 12
#define DI 24
#define DS 16
#define DC 4
#define DTR 4
#define NSEG 32
#define SEGLEN 64
#define LP 68   /* 68*4B = 272B rows: float4-aligned, 4-bank skew */

__device__ __forceinline__ float silu_f(float v) { return v / (1.f + __expf(-v)); }
__device__ __forceinline__ float softplus_f(float v) {
    return fmaxf(v, 0.f) + __logf(1.f + __expf(-fabsf(v)));
}
__device__ __forceinline__ float dot12w(float4 w0, float4 w1, float4 w2,
                                        float4 r0, float4 r1, float4 r2) {
    float s = 0.f;
    s = fmaf(w0.x, r0.x, s); s = fmaf(w0.y, r0.y, s);
    s = fmaf(w0.z, r0.z, s); s = fmaf(w0.w, r0.w, s);
    s = fmaf(w1.x, r1.x, s); s = fmaf(w1.y, r1.y, s);
    s = fmaf(w1.z, r1.z, s); s = fmaf(w1.w, r1.w, s);
    s = fmaf(w2.x, r2.x, s); s = fmaf(w2.y, r2.y, s);
    s = fmaf(w2.z, r2.z, s); s = fmaf(w2.w, r2.w, s);
    return s;
}

// One WAVE per (batch, segment): block = 64 threads, grid = 2048.
// Lane t owns timestep t0+t; all 24 channels computed per lane in registers.
// Weights are wave-uniform -> scalar loads. Barriers are single-wave (cheap).
// Scan: lane handles 6 (d,s) pairs (d = 4p + lane>>4, s = lane&15) -> 6-way ILP.
__global__ __launch_bounds__(64) void fused_wave_kernel(
    const float* __restrict__ x, const float* __restrict__ ipw,
    const float* __restrict__ cw, const float* __restrict__ cb,
    const float* __restrict__ xpw, const float* __restrict__ dpw,
    const float* __restrict__ dpb, const float* __restrict__ A_log,
    float* __restrict__ segA, float* __restrict__ segB)
{
    __shared__ __align__(16) float dts_s[DI][LP];  // dt
    __shared__ __align__(16) float dus_s[DI][LP];  // xin (phase A, col=row+3) then du
    __shared__ __align__(16) float Bs_s[DS][LP];   // B

    const int lane = threadIdx.x;           // == t
    const int b = blockIdx.x >> 5, seg = blockIdx.x & 31;
    const int t0 = seg * SEGLEN;
    const int t = lane;

    // ---- Phase A0: conv halo, 72 (halo-row, d) pairs spread over lanes ----
#pragma unroll
    for (int rep = 0; rep < 2; ++rep) {
        int pp = lane + rep * 64;
        if (pp < 3 * DI) {
            int hr = pp / DI, d = pp % DI;
            int row = t0 - 3 + hr;
            float v = 0.f;
            if (row >= 0) {
                const float4* xp = (const float4*)(x + ((size_t)b * SEQ + row) * DM);
                const float4* wp = (const float4*)(ipw + d * DM);
                v = dot12w(wp[0], wp[1], wp[2], xp[0], xp[1], xp[2]);
            }
            dus_s[d][hr] = v;
        }
    }

    // ---- Phase A1: xin = in_proj(x_row) for all 24 channels ----
    {
        const float4* xp = (const float4*)(x + ((size_t)b * SEQ + (t0 + t)) * DM);
        float4 r0 = xp[0], r1 = xp[1], r2 = xp[2];
#pragma unroll
        for (int d = 0; d < DI; ++d) {
            const float4* wp = (const float4*)(ipw + d * DM);
            dus_s[d][t + 3] = dot12w(wp[0], wp[1], wp[2], r0, r1, r2);
        }
    }
    __syncthreads();

    // ---- Phase A2: causal conv + silu -> xc in registers ----
    float xc[DI];
#pragma unroll
    for (int d = 0; d < DI; ++d) {
        const float4 c4 = *(const float4*)(cw + d * DC);
        float acc = cb[d];
        acc = fmaf(c4.x, dus_s[d][t + 0], acc);
        acc = fmaf(c4.y, dus_s[d][t + 1], acc);
        acc = fmaf(c4.z, dus_s[d][t + 2], acc);
        acc = fmaf(c4.w, dus_s[d][t + 3], acc);
        xc[d] = silu_f(acc);
    }
    __syncthreads();   // WAR: dus_s gets overwritten with du below

    // ---- Phase B: x_proj rows 0..19 (dt_raw 0..3, B 4..19) ----
    float dt_raw[DTR];
#pragma unroll
    for (int r = 0; r < DTR + DS; ++r) {
        const float4* wr = (const float4*)(xpw + r * DI);
        float s = 0.f;
#pragma unroll
        for (int c = 0; c < 6; ++c) {
            float4 w4 = wr[c];
            s = fmaf(w4.x, xc[4 * c + 0], s);
            s = fmaf(w4.y, xc[4 * c + 1], s);
            s = fmaf(w4.z, xc[4 * c + 2], s);
            s = fmaf(w4.w, xc[4 * c + 3], s);
        }
        if (r < DTR) dt_raw[r] = s;
        else         Bs_s[r - DTR][t] = s;
    }

    // ---- Phase C: dt = softplus(...); du = dt*xc ----
#pragma unroll
    for (int d = 0; d < DI; ++d) {
        const float4 w4 = *(const float4*)(dpw + d * DTR);
        float sv = dpb[d];
        sv = fmaf(dt_raw[0], w4.x, sv); sv = fmaf(dt_raw[1], w4.y, sv);
        sv = fmaf(dt_raw[2], w4.z, sv); sv = fmaf(dt_raw[3], w4.w, sv);
        float dt = softplus_f(sv);
        dts_s[d][t] = dt;
        dus_s[d][t] = dt * xc[d];
    }
    __syncthreads();

    // ---- Scan: 6 (d,s) pairs per lane, 64 steps, affine reduction ----
    {
        const int s_ = lane & 15;
        const int db = lane >> 4;
        float Ap[6], aa[6], ba[6];
#pragma unroll
        for (int p = 0; p < 6; ++p) {
            Ap[p] = -__expf(A_log[(4 * p + db) * DS + s_]);
            aa[p] = 1.f; ba[p] = 0.f;
        }
#pragma unroll 2
        for (int i = 0; i < SEGLEN / 4; ++i) {
            const float4 B4 = *(const float4*)&Bs_s[s_][4 * i];
#pragma unroll
            for (int p = 0; p < 6; ++p) {
                const int d = 4 * p + db;
                const float4 dt4 = *(const float4*)&dts_s[d][4 * i];
                const float4 du4 = *(const float4*)&dus_s[d][4 * i];
                float a;
                a = __expf(dt4.x * Ap[p]); ba[p] = fmaf(a, ba[p], du4.x * B4.x); aa[p] *= a;
                a = __expf(dt4.y * Ap[p]); ba[p] = fmaf(a, ba[p], du4.y * B4.y); aa[p] *= a;
                a = __expf(dt4.z * Ap[p]); ba[p] = fmaf(a, ba[p], du4.z * B4.z); aa[p] *= a;
                a = __expf(dt4.w * Ap[p]); ba[p] = fmaf(a, ba[p], du4.w * B4.w); aa[p] *= a;
            }
        }
        const size_t base = (size_t)blockIdx.x * (DI * DS);
#pragma unroll
        for (int p = 0; p < 6; ++p) {
            segA[base + 64 * p + lane] = aa[p];
            segB[base + 64 * p + lane] = ba[p];
        }
    }
}

// One block per batch: combine 32 segments + tiny epilogue.
__global__ __launch_bounds__(384) void finish_kernel(
    const float* __restrict__ segA, const float* __restrict__ segB,
    const float* __restrict__ x, const float* __restrict__ ipw,
    const float* __restrict__ cw, const float* __restrict__ cb,
    const float* __restrict__ xpw, const float* __restrict__ Dv,
    const float* __restrict__ opw, const float* __restrict__ fcw,
    const float* __restrict__ fcb, float* __restrict__ out)
{
    int b = blockIdx.x, tid = threadIdx.x;

    float h = 0.f;
#pragma unroll
    for (int g = 0; g < NSEG; ++g) {
        size_t o = ((size_t)(b * NSEG + g)) * (DI * DS) + tid;
        h = fmaf(segA[o], h, segB[o]);
    }

    __shared__ float h_sh[DI * DS];
    __shared__ float xcl[DI], CL[DS], zv[DI], yv[DI], ov[DM];
    h_sh[tid] = h;

    const float* xr = x + ((size_t)b * SEQ + SEQ - 1) * DM;
    if (tid < DI) {
        float acc = cb[tid];
#pragma unroll
        for (int k = 0; k < DC; ++k) {
            const float* row = x + ((size_t)b * SEQ + (SEQ - DC + k)) * DM;
            float xin = 0.f;
#pragma unroll
            for (int m = 0; m < DM; ++m) xin = fmaf(row[m], ipw[tid * DM + m], xin);
            acc = fmaf(xin, cw[tid * DC + k], acc);
        }
        xcl[tid] = silu_f(acc);
        float s = 0.f;
#pragma unroll
        for (int m = 0; m < DM; ++m) s = fmaf(xr[m], ipw[(DI + tid) * DM + m], s);
        zv[tid] = s;
    }
    __syncthreads();

    if (tid < DS) {
        float s = 0.f;
#pragma unroll
        for (int d = 0; d < DI; ++d) s = fmaf(xcl[d], xpw[(DTR + DS + tid) * DI + d], s);
        CL[tid] = s;
    }
    __syncthreads();

    if (tid < DI) {
        float y = 0.f;
#pragma unroll
        for (int s2 = 0; s2 < DS; ++s2) y = fmaf(h_sh[tid * DS + s2], CL[s2], y);
        y = fmaf(xcl[tid], Dv[tid], y);
        yv[tid] = y * silu_f(zv[tid]);
    }
    __syncthreads();

    if (tid < DM) {
        float s = 0.f;
#pragma unroll
        for (int d = 0; d < DI; ++d) s = fmaf(yv[d], opw[tid * DI + d], s);
        ov[tid] = s;
    }
    __syncthreads();

    if (tid == 0) {
        float s = fcb[0];
#pragma unroll
        for (int e = 0; e < DM; ++e) s = fmaf(ov[e], fcw[e], s);
        out[b] = s;
    }
}

extern "C" void kernel_launch(void* const* d_in, const int* in_sizes, int n_in,
                              void* d_out, int out_size, void* d_ws, size_t ws_size,
                              hipStream_t stream)
{
    const float* x   = (const float*)d_in[0];
    const float* ipw = (const float*)d_in[1];
    const float* cw  = (const float*)d_in[2];
    const float* cb  = (const float*)d_in[3];
    const float* xpw = (const float*)d_in[4];
    const float* dpw = (const float*)d_in[5];
    const float* dpb = (const float*)d_in[6];
    const float* Al  = (const float*)d_in[7];
    const float* Dv  = (const float*)d_in[8];
    const float* opw = (const float*)d_in[9];
    const float* fcw = (const float*)d_in[10];
    const float* fcb = (const float*)d_in[11];

    float* segA = (float*)d_ws;                            // [B*NSEG][384]
    float* segB = segA + (size_t)B_SZ * NSEG * DI * DS;

    fused_wave_kernel<<<B_SZ * NSEG, 64, 0, stream>>>(
        x, ipw, cw, cb, xpw, dpw, dpb, Al, segA, segB);
    finish_kernel<<<B_SZ, 384, 0, stream>>>(
        segA, segB, x, ipw, cw, cb, xpw, Dv, opw, fcw, fcb, (float*)d_out);
}

// Round 6
// 106.777 us; speedup vs baseline: 1.4910x; 1.0256x over previous
//
#include <hip/hip_runtime.h>
#include <math.h>

#define B_SZ 64
#define SEQ 2048
#define DM 12
#define DI 24
#define DS 16
#define DC 4
#define DTR 4
#define NSEG 32
#define SEGLEN 64
#define LP 68   /* 272 B rows: float4-aligned, 4-bank skew per row */

__device__ __forceinline__ float silu_f(float v) { return v / (1.f + __expf(-v)); }
__device__ __forceinline__ float softplus_f(float v) {
    return fmaxf(v, 0.f) + __logf(1.f + __expf(-fabsf(v)));
}
__device__ __forceinline__ float dot12w(float4 w0, float4 w1, float4 w2,
                                        float4 r0, float4 r1, float4 r2) {
    float s = 0.f;
    s = fmaf(w0.x, r0.x, s); s = fmaf(w0.y, r0.y, s);
    s = fmaf(w0.z, r0.z, s); s = fmaf(w0.w, r0.w, s);
    s = fmaf(w1.x, r1.x, s); s = fmaf(w1.y, r1.y, s);
    s = fmaf(w1.z, r1.z, s); s = fmaf(w1.w, r1.w, s);
    s = fmaf(w2.x, r2.x, s); s = fmaf(w2.y, r2.y, s);
    s = fmaf(w2.z, r2.z, s); s = fmaf(w2.w, r2.w, s);
    return s;
}

// One block = 2 waves per (batch, segment); grid = 2048. 16 waves/CU resident.
// Phases: wave = channel half (wave h owns channels 12h..12h+11), lane = timestep.
// Scan: 384 (d,s) pairs over 128 threads -> 3 pairs/thread, 64 serial steps.
// LDS aliasing: dtxc = xc (A2->B) then dt (C->scan); duxin = xin (A->A2) then du.
__global__ __launch_bounds__(128) void fused2_kernel(
    const float* __restrict__ x, const float* __restrict__ ipw,
    const float* __restrict__ cw, const float* __restrict__ cb,
    const float* __restrict__ xpw, const float* __restrict__ dpw,
    const float* __restrict__ dpb, const float* __restrict__ A_log,
    float* __restrict__ segA, float* __restrict__ segB)
{
    __shared__ __align__(16) float dtxc_s[DI][LP];
    __shared__ __align__(16) float duxin_s[DI][LP];
    __shared__ __align__(16) float Bs_s[DS][LP];
    __shared__ __align__(16) float dtr_s[DTR][LP];

    const int tid = threadIdx.x;
    const int b = blockIdx.x >> 5, seg = blockIdx.x & 31;
    const int t0 = seg * SEGLEN;
    const int t = tid & 63;          // timestep within segment (per wave)
    const int half = tid >> 6;       // wave id: channel half
    const int dlo = half * 12;

    // ---- Phase A0: conv halo — 72 (halo-row, channel) units over 128 threads ----
    if (tid < 3 * DI) {
        int hr = tid / DI, d = tid % DI;
        int row = t0 - 3 + hr;
        float v = 0.f;
        if (row >= 0) {
            const float4* xp = (const float4*)(x + ((size_t)b * SEQ + row) * DM);
            const float4* wp = (const float4*)(ipw + d * DM);
            v = dot12w(wp[0], wp[1], wp[2], xp[0], xp[1], xp[2]);
        }
        duxin_s[d][hr] = v;
    }

    // ---- Phase A1: xin = in_proj(x_t) for own 12 channels ----
    {
        const float4* xp = (const float4*)(x + ((size_t)b * SEQ + (t0 + t)) * DM);
        float4 r0 = xp[0], r1 = xp[1], r2 = xp[2];
#pragma unroll
        for (int i = 0; i < 12; ++i) {
            const float4* wp = (const float4*)(ipw + (dlo + i) * DM);
            duxin_s[dlo + i][t + 3] = dot12w(wp[0], wp[1], wp[2], r0, r1, r2);
        }
    }
    __syncthreads();

    // ---- Phase A2: causal conv + silu for own 12 channels; xc -> regs + LDS ----
    float xc_reg[12];
#pragma unroll
    for (int i = 0; i < 12; ++i) {
        int d = dlo + i;
        const float4 c4 = *(const float4*)(cw + d * DC);
        float acc = cb[d];
        acc = fmaf(c4.x, duxin_s[d][t + 0], acc);
        acc = fmaf(c4.y, duxin_s[d][t + 1], acc);
        acc = fmaf(c4.z, duxin_s[d][t + 2], acc);
        acc = fmaf(c4.w, duxin_s[d][t + 3], acc);
        float v = silu_f(acc);
        xc_reg[i] = v;
        dtxc_s[d][t] = v;
    }
    __syncthreads();

    // ---- Phase B: x_proj rows 10*half .. 10*half+9 (dt_raw 0..3, B 4..19) ----
    {
        float xcv[DI];
#pragma unroll
        for (int d = 0; d < DI; ++d) xcv[d] = dtxc_s[d][t];
#pragma unroll
        for (int q = 0; q < 10; ++q) {
            int r = half * 10 + q;
            const float4* wr = (const float4*)(xpw + r * DI);
            float s = 0.f;
#pragma unroll
            for (int c = 0; c < 6; ++c) {
                float4 w4 = wr[c];
                s = fmaf(w4.x, xcv[4 * c + 0], s);
                s = fmaf(w4.y, xcv[4 * c + 1], s);
                s = fmaf(w4.z, xcv[4 * c + 2], s);
                s = fmaf(w4.w, xcv[4 * c + 3], s);
            }
            if (r < DTR) dtr_s[r][t] = s;
            else         Bs_s[r - DTR][t] = s;
        }
    }
    __syncthreads();

    // ---- Phase C: dt = softplus(dt_raw @ dpw^T + dpb); dt,du -> LDS ----
    {
        float d0 = dtr_s[0][t], d1 = dtr_s[1][t], d2 = dtr_s[2][t], d3 = dtr_s[3][t];
#pragma unroll
        for (int i = 0; i < 12; ++i) {
            int d = dlo + i;
            const float4 w4 = *(const float4*)(dpw + d * DTR);
            float sv = dpb[d];
            sv = fmaf(d0, w4.x, sv); sv = fmaf(d1, w4.y, sv);
            sv = fmaf(d2, w4.z, sv); sv = fmaf(d3, w4.w, sv);
            float dt = softplus_f(sv);
            dtxc_s[d][t] = dt;               // overwrites xc (dead after B)
            duxin_s[d][t] = dt * xc_reg[i];  // du (xin dead after A2)
        }
    }
    __syncthreads();

    // ---- Scan: 3 (d,s) pairs/thread, d = 8p + (tid>>4 & 7 -> via dq), s = tid&15 ----
    {
        const int s_ = tid & 15;
        const int dq = tid >> 4;             // 0..7 across both waves
        float Ap[3], aa[3], ba[3];
#pragma unroll
        for (int p = 0; p < 3; ++p) {
            Ap[p] = -__expf(A_log[128 * p + tid]);  // (8p+dq)*16+s_ == 128p+tid
            aa[p] = 1.f; ba[p] = 0.f;
        }
#pragma unroll 4
        for (int i = 0; i < SEGLEN / 4; ++i) {
            const float4 B4 = *(const float4*)&Bs_s[s_][4 * i];
#pragma unroll
            for (int p = 0; p < 3; ++p) {
                const int d = 8 * p + dq;
                const float4 dt4 = *(const float4*)&dtxc_s[d][4 * i];
                const float4 du4 = *(const float4*)&duxin_s[d][4 * i];
                float a;
                a = __expf(dt4.x * Ap[p]); ba[p] = fmaf(a, ba[p], du4.x * B4.x); aa[p] *= a;
                a = __expf(dt4.y * Ap[p]); ba[p] = fmaf(a, ba[p], du4.y * B4.y); aa[p] *= a;
                a = __expf(dt4.z * Ap[p]); ba[p] = fmaf(a, ba[p], du4.z * B4.z); aa[p] *= a;
                a = __expf(dt4.w * Ap[p]); ba[p] = fmaf(a, ba[p], du4.w * B4.w); aa[p] *= a;
            }
        }
        const size_t base = (size_t)blockIdx.x * (DI * DS);
#pragma unroll
        for (int p = 0; p < 3; ++p) {
            segA[base + 128 * p + tid] = aa[p];
            segB[base + 128 * p + tid] = ba[p];
        }
    }
}

// One block per batch: combine 32 segments + tiny epilogue.
__global__ __launch_bounds__(384) void finish_kernel(
    const float* __restrict__ segA, const float* __restrict__ segB,
    const float* __restrict__ x, const float* __restrict__ ipw,
    const float* __restrict__ cw, const float* __restrict__ cb,
    const float* __restrict__ xpw, const float* __restrict__ Dv,
    const float* __restrict__ opw, const float* __restrict__ fcw,
    const float* __restrict__ fcb, float* __restrict__ out)
{
    int b = blockIdx.x, tid = threadIdx.x;

    float h = 0.f;
#pragma unroll
    for (int g = 0; g < NSEG; ++g) {
        size_t o = ((size_t)(b * NSEG + g)) * (DI * DS) + tid;
        h = fmaf(segA[o], h, segB[o]);
    }

    __shared__ float h_sh[DI * DS];
    __shared__ float xcl[DI], CL[DS], zv[DI], yv[DI], ov[DM];
    h_sh[tid] = h;

    const float* xr = x + ((size_t)b * SEQ + SEQ - 1) * DM;
    if (tid < DI) {
        float acc = cb[tid];
#pragma unroll
        for (int k = 0; k < DC; ++k) {
            const float* row = x + ((size_t)b * SEQ + (SEQ - DC + k)) * DM;
            float xin = 0.f;
#pragma unroll
            for (int m = 0; m < DM; ++m) xin = fmaf(row[m], ipw[tid * DM + m], xin);
            acc = fmaf(xin, cw[tid * DC + k], acc);
        }
        xcl[tid] = silu_f(acc);
        float s = 0.f;
#pragma unroll
        for (int m = 0; m < DM; ++m) s = fmaf(xr[m], ipw[(DI + tid) * DM + m], s);
        zv[tid] = s;
    }
    __syncthreads();

    if (tid < DS) {
        float s = 0.f;
#pragma unroll
        for (int d = 0; d < DI; ++d) s = fmaf(xcl[d], xpw[(DTR + DS + tid) * DI + d], s);
        CL[tid] = s;
    }
    __syncthreads();

    if (tid < DI) {
        float y = 0.f;
#pragma unroll
        for (int s2 = 0; s2 < DS; ++s2) y = fmaf(h_sh[tid * DS + s2], CL[s2], y);
        y = fmaf(xcl[tid], Dv[tid], y);
        yv[tid] = y * silu_f(zv[tid]);
    }
    __syncthreads();

    if (tid < DM) {
        float s = 0.f;
#pragma unroll
        for (int d = 0; d < DI; ++d) s = fmaf(yv[d], opw[tid * DI + d], s);
        ov[tid] = s;
    }
    __syncthreads();

    if (tid == 0) {
        float s = fcb[0];
#pragma unroll
        for (int e = 0; e < DM; ++e) s = fmaf(ov[e], fcw[e], s);
        out[b] = s;
    }
}

extern "C" void kernel_launch(void* const* d_in, const int* in_sizes, int n_in,
                              void* d_out, int out_size, void* d_ws, size_t ws_size,
                              hipStream_t stream)
{
    const float* x   = (const float*)d_in[0];
    const float* ipw = (const float*)d_in[1];
    const float* cw  = (const float*)d_in[2];
    const float* cb  = (const float*)d_in[3];
    const float* xpw = (const float*)d_in[4];
    const float* dpw = (const float*)d_in[5];
    const float* dpb = (const float*)d_in[6];
    const float* Al  = (const float*)d_in[7];
    const float* Dv  = (const float*)d_in[8];
    const float* opw = (const float*)d_in[9];
    const float* fcw = (const float*)d_in[10];
    const float* fcb = (const float*)d_in[11];

    float* segA = (float*)d_ws;                            // [B*NSEG][384]
    float* segB = segA + (size_t)B_SZ * NSEG * DI * DS;

    fused2_kernel<<<B_SZ * NSEG, 128, 0, stream>>>(
        x, ipw, cw, cb, xpw, dpw, dpb, Al, segA, segB);
    finish_kernel<<<B_SZ, 384, 0, stream>>>(
        segA, segB, x, ipw, cw, cb, xpw, Dv, opw, fcw, fcb, (float*)d_out);
}